// Round 2
// baseline (882.170 us; speedup 1.0000x reference)
//
#include <hip/hip_runtime.h>
#include <hip/hip_bf16.h>
#include <stdint.h>

#define D_DIM 1024
#define E_NUM 8
#define H_DIM 4096

typedef __attribute__((ext_vector_type(8))) short short8;
typedef __attribute__((ext_vector_type(4))) short short4v;
typedef __attribute__((ext_vector_type(4))) unsigned short ushort4v;
typedef __attribute__((ext_vector_type(4))) float f32x4;

#define GLOBAL_AS __attribute__((address_space(1)))
#define LDS_AS __attribute__((address_space(3)))

__device__ __forceinline__ void async_load16(const void* g, void* l) {
    __builtin_amdgcn_global_load_lds((GLOBAL_AS void*)g, (LDS_AS void*)l, 16, 0, 0);
}

// tanh-form gelu, branchless. |err| <= ~3e-4.
__device__ __forceinline__ float gelu_fast(float x) {
    float x3 = x * x * x;
    float z = 0.7978845608028654f * x + 0.0356774081363001f * x3;
    float u = __expf(-2.0f * fabsf(z));
    float t = __fdividef(1.0f - u, 1.0f + u);
    t = copysignf(t, z);
    return 0.5f * x * (1.0f + t);
}

__device__ __forceinline__ float b2f(short s) {
    union { float f; unsigned u; } x; x.u = ((unsigned)(unsigned short)s) << 16; return x.f;
}

__device__ __forceinline__ unsigned short f2b(float f) {
    union { __hip_bfloat16 h; unsigned short s; } u;
    u.h = __float2bfloat16(f);
    return u.s;
}

// ---------------- router: logits (fp64), softmax, top-2; NO global atomics; fused x->bf16 ----------------
__global__ __launch_bounds__(256) void router_kernel(
    const float* __restrict__ x, const float* __restrict__ Wg,
    __hip_bfloat16* __restrict__ xb, int* __restrict__ epick,
    float* __restrict__ ewgt, int T) {
    int gwave = (int)((blockIdx.x * 256 + threadIdx.x) >> 6);
    int lane = threadIdx.x & 63;
    if (gwave >= T) return;
    const float* xr = x + (size_t)gwave * D_DIM;
    double acc[E_NUM];
#pragma unroll
    for (int e = 0; e < E_NUM; ++e) acc[e] = 0.0;
#pragma unroll
    for (int i = 0; i < D_DIM / 64; ++i) {
        int d = i * 64 + lane;
        float xv = xr[d];
        xb[(size_t)gwave * D_DIM + d] = __float2bfloat16(xv);
        const float4* wgp = (const float4*)(Wg + (size_t)d * E_NUM);
        float4 wa = wgp[0], wb = wgp[1];
        double xd = (double)xv;
        acc[0] += xd * (double)wa.x; acc[1] += xd * (double)wa.y;
        acc[2] += xd * (double)wa.z; acc[3] += xd * (double)wa.w;
        acc[4] += xd * (double)wb.x; acc[5] += xd * (double)wb.y;
        acc[6] += xd * (double)wb.z; acc[7] += xd * (double)wb.w;
    }
#pragma unroll
    for (int s = 32; s > 0; s >>= 1) {
#pragma unroll
        for (int e = 0; e < E_NUM; ++e) acc[e] += __shfl_xor(acc[e], s);
    }
    double mx = acc[0];
#pragma unroll
    for (int e = 1; e < E_NUM; ++e) mx = fmax(mx, acc[e]);
    double p[E_NUM]; double sum = 0.0;
#pragma unroll
    for (int e = 0; e < E_NUM; ++e) { p[e] = exp(acc[e] - mx); sum += p[e]; }
    int i0 = 0;
#pragma unroll
    for (int e = 1; e < E_NUM; ++e) if (p[e] > p[i0]) i0 = e;
    int i1 = (i0 == 0) ? 1 : 0;
#pragma unroll
    for (int e = 0; e < E_NUM; ++e) if (e != i0 && p[e] > p[i1]) i1 = e;
    if (lane == 0) {
        epick[gwave] = i0 | (i1 << 8);
        ewgt[2 * gwave]     = (float)(p[i0] / sum);
        ewgt[2 * gwave + 1] = (float)(p[i1] / sum);
    }
}

// ---------------- bucket: block-aggregated scatter; 8 global atomics per block ----------------
__global__ __launch_bounds__(256) void bucket_kernel(
    const int* __restrict__ epick, int* __restrict__ cnt,
    int* __restrict__ tok, int* __restrict__ eidx, int T) {
    __shared__ int lcnt[E_NUM];
    __shared__ int gbase[E_NUM];
    int b = blockIdx.x, tid = threadIdx.x;
    if (tid < E_NUM) lcnt[tid] = 0;
    __syncthreads();
    int t = b * 128 + (tid >> 1);
    int j = tid & 1;
    int e = (epick[t] >> (j * 8)) & 0xff;
    int li = atomicAdd(&lcnt[e], 1);
    __syncthreads();
    if (tid < E_NUM) gbase[tid] = atomicAdd(&cnt[tid], lcnt[tid]);
    __syncthreads();
    int slot = gbase[e] + li;
    tok[e * T + slot] = t;
    eidx[2 * t + j] = (e << 16) | slot;
}

__global__ void prefix_kernel(const int* __restrict__ cnt, int* __restrict__ base) {
    if (threadIdx.x == 0) {
        int a = 0;
#pragma unroll
        for (int e = 0; e < E_NUM; ++e) { base[e] = a; a += cnt[e]; }
    }
}

// ---------------- unified W1/W2 transpose, 64x64 tiles, packed stores ----------------
// W1: [E][D][H] f32 -> w1t [E][H][D] bf16 (no perm).
// W2: [E][H][D] f32 -> w2t [E][D][H] bf16 with K(=H) perm pi(j)=(j&3)*16+(j>>2) per 64-block.
__global__ __launch_bounds__(256) void transpose_both_kernel(
    const float* __restrict__ W1, const float* __restrict__ W2,
    __hip_bfloat16* __restrict__ w1t, __hip_bfloat16* __restrict__ w2t) {
    __shared__ float tile[64][65];
    int e = blockIdx.z;
    int id = blockIdx.x;
    const float* src; unsigned short* dst; int R, C, r0, c0, perm;
    if (id < 1024) {  // W1: R=D rows, C=H cols
        R = D_DIM; C = H_DIM;
        r0 = (id >> 6) * 64; c0 = (id & 63) * 64;
        src = W1 + (size_t)e * D_DIM * H_DIM;
        dst = (unsigned short*)(w1t + (size_t)e * H_DIM * D_DIM);
        perm = 0;
    } else {          // W2: R=H rows, C=D cols
        id -= 1024;
        R = H_DIM; C = D_DIM;
        r0 = (id >> 4) * 64; c0 = (id & 15) * 64;
        src = W2 + (size_t)e * H_DIM * D_DIM;
        dst = (unsigned short*)(w2t + (size_t)e * D_DIM * H_DIM);
        perm = 1;
    }
    int tx = threadIdx.x, ty = threadIdx.y;  // 32 x 8
#pragma unroll
    for (int i = 0; i < 8; ++i) {
        int j = ty + i * 8;
        int sr = perm ? ((j & 3) * 16 + (j >> 2)) : j;
        float2 v = *(const float2*)(src + (size_t)(r0 + sr) * C + c0 + 2 * tx);
        tile[j][2 * tx] = v.x; tile[j][2 * tx + 1] = v.y;
    }
    __syncthreads();
#pragma unroll
    for (int i = 0; i < 8; ++i) {
        int cc = ty + i * 8;
        unsigned pk = (unsigned)f2b(tile[2 * tx][cc]) | ((unsigned)f2b(tile[2 * tx + 1][cc]) << 16);
        *(unsigned*)(dst + (size_t)(c0 + cc) * R + r0 + 2 * tx) = pk;
    }
}

// ====================== 256x256 deep-pipelined GEMMs ======================
// Geometry: BM=BN=256, BK=32, 512 threads = 8 waves (2M x 4N), wave tile
// 128x64, acc[8][4] (128 VGPR). LDS: 4 K-tile buffers x (A 16KB + B 16KB)
// = 128 KB -> 1 block/CU (8 waves).
// Pipeline (T3+T4+T5): explicit vmcnt(0) drain before stage(0) makes the
// per-wave count exact (4 loads/tile/thread). Prologue stages tiles 0..2
// (12 in flight); body t stages tile t+3 into buf[(t+3)&3] (== buf[(t-1)&3],
// whose ds_reads completed before the previous barrier), computes buf[t&3],
// then `s_waitcnt vmcnt(8)` (leaves tiles t+2,t+3 in flight; guarantees
// tile t+1 landed — vmcnt retires in order) + raw s_barrier. Tail peels
// vmcnt(4)/vmcnt(0). Raw s_barrier (not __syncthreads) avoids the
// compiler's vmcnt(0) drain (m218: counted-vs-drain0 +38-73%).
// LDS swizzle: proven BK=32 K-chunk scheme (row r chunk k at chunk
// r*4 + (k ^ ((r>>1)&3)); writer pre-swizzles the global source chunk,
// global_load_lds dest stays linear). Measured 0 bank conflicts.

// ---------------- GEMM1: h[slot, perm(col)] = gelu(x[tok] @ W1[e] + b1[e]) ----------------
__global__ __launch_bounds__(512) void gemm1_kernel(
    const __hip_bfloat16* __restrict__ xb,   // [T][D]
    const __hip_bfloat16* __restrict__ w1t,  // [E][H][D] (B^T)
    const float* __restrict__ b1,            // [E][H]
    const int* __restrict__ cnt, const int* __restrict__ base,
    const int* __restrict__ tok,
    __hip_bfloat16* __restrict__ hbuf,       // [2T][H] (N-permuted)
    int T) {
    int e = blockIdx.z;
    int M = cnt[e];
    int m0 = blockIdx.y * 256;
    if (m0 >= M) return;
    int n0 = blockIdx.x * 256;
    const __hip_bfloat16* Bp = w1t + (size_t)e * H_DIM * D_DIM;

    __shared__ __align__(16) short sA[4][256 * 32];
    __shared__ __align__(16) short sB[4][256 * 32];
    __shared__ float sBias[256];

    int tid = threadIdx.x;
    int w = tid >> 6, lane = tid & 63;
    int wm = w >> 2, wn = w & 3;
    int q = lane >> 4, l4 = lane & 15;

    if (tid < 256) sBias[tid] = b1[e * H_DIM + n0 + tid];

    int kswz = ((lane & 3) ^ ((lane >> 3) & 3)) << 3;  // pre-swizzled global chunk
    int r0 = w * 32 + (lane >> 2);
    int r1 = r0 + 16;
    int tA0 = tok[e * T + min(m0 + r0, M - 1)];
    int tA1 = tok[e * T + min(m0 + r1, M - 1)];
    const __hip_bfloat16* gA0 = xb + (size_t)tA0 * D_DIM + kswz;
    const __hip_bfloat16* gA1 = xb + (size_t)tA1 * D_DIM + kswz;
    const __hip_bfloat16* gB0 = Bp + (size_t)(n0 + r0) * D_DIM + kswz;
    const __hip_bfloat16* gB1 = Bp + (size_t)(n0 + r1) * D_DIM + kswz;

    f32x4 acc[8][4];
#pragma unroll
    for (int a = 0; a < 8; ++a)
#pragma unroll
        for (int b = 0; b < 4; ++b) acc[a][b] = (f32x4){0.f, 0.f, 0.f, 0.f};

    auto stage = [&](int tt) {
        int bi = tt & 3, kk = tt * 32;
        char* la = (char*)sA[bi] + w * 2048;   // wave-uniform dest; HW adds lane*16
        char* lb = (char*)sB[bi] + w * 2048;
        async_load16(gA0 + kk, la);
        async_load16(gA1 + kk, la + 1024);
        async_load16(gB0 + kk, lb);
        async_load16(gB1 + kk, lb + 1024);
    };
    auto body = [&](int tt) {
        const char* pa = (const char*)sA[tt & 3];
        const char* pb = (const char*)sB[tt & 3];
        short8 bF[4];
#pragma unroll
        for (int n = 0; n < 4; ++n) {
            int rb = wn * 64 + n * 16 + l4;
            bF[n] = *(const short8*)(pb + rb * 64 + ((q ^ ((rb >> 1) & 3)) << 4));
        }
        __builtin_amdgcn_s_setprio(1);
#pragma unroll
        for (int m = 0; m < 8; ++m) {
            int ra = wm * 128 + m * 16 + l4;
            short8 aF = *(const short8*)(pa + ra * 64 + ((q ^ ((ra >> 1) & 3)) << 4));
#pragma unroll
            for (int n = 0; n < 4; ++n)
                acc[m][n] = __builtin_amdgcn_mfma_f32_16x16x32_bf16(aF, bF[n], acc[m][n], 0, 0, 0);
        }
        __builtin_amdgcn_s_setprio(0);
    };

    const int nt = D_DIM / 32;  // 32
    asm volatile("s_waitcnt vmcnt(0)" ::: "memory");  // drain pre-pipeline loads; counts exact below
    stage(0); stage(1); stage(2);
    asm volatile("s_waitcnt vmcnt(8)" ::: "memory");
    __builtin_amdgcn_s_barrier();
    for (int t = 0; t < nt - 3; ++t) {
        stage(t + 3);
        body(t);
        asm volatile("s_waitcnt vmcnt(8)" ::: "memory");
        __builtin_amdgcn_s_barrier();
    }
    body(nt - 3);
    asm volatile("s_waitcnt vmcnt(4)" ::: "memory");
    __builtin_amdgcn_s_barrier();
    body(nt - 2);
    asm volatile("s_waitcnt vmcnt(0)" ::: "memory");
    __builtin_amdgcn_s_barrier();
    body(nt - 1);

    int sb = base[e];
    unsigned short* hs = (unsigned short*)hbuf;
#pragma unroll
    for (int m = 0; m < 8; ++m) {
        int rbase = wm * 128 + m * 16 + q * 4;
#pragma unroll
        for (int i = 0; i < 4; ++i) {
            int row = m0 + rbase + i;
            if (row < M) {
                size_t hrow = (size_t)(sb + row) * H_DIM;
                ushort4v pk;
#pragma unroll
                for (int n = 0; n < 4; ++n) {
                    float v = acc[m][n][i] + sBias[wn * 64 + n * 16 + l4];
                    pk[n] = f2b(gelu_fast(v));
                }
                *(ushort4v*)(hs + hrow + n0 + wn * 64 + l4 * 4) = pk;
            }
        }
    }
}

// ---------------- GEMM2 (split-K=2): ybuf[kc][slot, perm(col)] = partial(h @ W2[e]) ----------------
__global__ __launch_bounds__(512) void gemm2_kernel(
    const __hip_bfloat16* __restrict__ hbuf, // [2T][H] (K-permuted, matches w2t)
    const __hip_bfloat16* __restrict__ w2t,  // [E][D][H] (B^T, K-permuted)
    const int* __restrict__ cnt, const int* __restrict__ base,
    __hip_bfloat16* __restrict__ ybuf,       // [2][2T][D] (N-permuted)
    int T) {
    int e = blockIdx.z >> 1;
    int kc = blockIdx.z & 1;
    int M = cnt[e];
    int m0 = blockIdx.y * 256;
    if (m0 >= M) return;
    int n0 = blockIdx.x * 256;
    int sb = base[e];
    const __hip_bfloat16* Bp = w2t + (size_t)e * D_DIM * H_DIM;

    __shared__ __align__(16) short sA[4][256 * 32];
    __shared__ __align__(16) short sB[4][256 * 32];

    int tid = threadIdx.x;
    int w = tid >> 6, lane = tid & 63;
    int wm = w >> 2, wn = w & 3;
    int q = lane >> 4, l4 = lane & 15;

    int kswz = ((lane & 3) ^ ((lane >> 3) & 3)) << 3;
    int r0 = w * 32 + (lane >> 2);
    int r1 = r0 + 16;
    int k0 = kc * (H_DIM / 2);
    const __hip_bfloat16* gA0 = hbuf + (size_t)(sb + min(m0 + r0, M - 1)) * H_DIM + k0 + kswz;
    const __hip_bfloat16* gA1 = hbuf + (size_t)(sb + min(m0 + r1, M - 1)) * H_DIM + k0 + kswz;
    const __hip_bfloat16* gB0 = Bp + (size_t)(n0 + r0) * H_DIM + k0 + kswz;
    const __hip_bfloat16* gB1 = Bp + (size_t)(n0 + r1) * H_DIM + k0 + kswz;

    f32x4 acc[8][4];
#pragma unroll
    for (int a = 0; a < 8; ++a)
#pragma unroll
        for (int b = 0; b < 4; ++b) acc[a][b] = (f32x4){0.f, 0.f, 0.f, 0.f};

    auto stage = [&](int tt) {
        int bi = tt & 3, kk = tt * 32;
        char* la = (char*)sA[bi] + w * 2048;
        char* lb = (char*)sB[bi] + w * 2048;
        async_load16(gA0 + kk, la);
        async_load16(gA1 + kk, la + 1024);
        async_load16(gB0 + kk, lb);
        async_load16(gB1 + kk, lb + 1024);
    };
    auto body = [&](int tt) {
        const char* pa = (const char*)sA[tt & 3];
        const char* pb = (const char*)sB[tt & 3];
        short8 bF[4];
#pragma unroll
        for (int n = 0; n < 4; ++n) {
            int rb = wn * 64 + n * 16 + l4;
            bF[n] = *(const short8*)(pb + rb * 64 + ((q ^ ((rb >> 1) & 3)) << 4));
        }
        __builtin_amdgcn_s_setprio(1);
#pragma unroll
        for (int m = 0; m < 8; ++m) {
            int ra = wm * 128 + m * 16 + l4;
            short8 aF = *(const short8*)(pa + ra * 64 + ((q ^ ((ra >> 1) & 3)) << 4));
#pragma unroll
            for (int n = 0; n < 4; ++n)
                acc[m][n] = __builtin_amdgcn_mfma_f32_16x16x32_bf16(aF, bF[n], acc[m][n], 0, 0, 0);
        }
        __builtin_amdgcn_s_setprio(0);
    };

    const int nt = (H_DIM / 2) / 32;  // 64
    asm volatile("s_waitcnt vmcnt(0)" ::: "memory");
    stage(0); stage(1); stage(2);
    asm volatile("s_waitcnt vmcnt(8)" ::: "memory");
    __builtin_amdgcn_s_barrier();
    for (int t = 0; t < nt - 3; ++t) {
        stage(t + 3);
        body(t);
        asm volatile("s_waitcnt vmcnt(8)" ::: "memory");
        __builtin_amdgcn_s_barrier();
    }
    body(nt - 3);
    asm volatile("s_waitcnt vmcnt(4)" ::: "memory");
    __builtin_amdgcn_s_barrier();
    body(nt - 2);
    asm volatile("s_waitcnt vmcnt(0)" ::: "memory");
    __builtin_amdgcn_s_barrier();
    body(nt - 1);

    size_t ybase = (size_t)kc * 2 * T;
    unsigned short* ys = (unsigned short*)ybuf;
#pragma unroll
    for (int m = 0; m < 8; ++m) {
        int rbase = wm * 128 + m * 16 + q * 4;
#pragma unroll
        for (int i = 0; i < 4; ++i) {
            int row = m0 + rbase + i;
            if (row < M) {
                size_t yrow = (ybase + sb + row) * D_DIM;
                ushort4v pk;
#pragma unroll
                for (int n = 0; n < 4; ++n) pk[n] = f2b(acc[m][n][i]);
                *(ushort4v*)(ys + yrow + n0 + wn * 64 + l4 * 4) = pk;
            }
        }
    }
}

// ---------------- combine: out[t, pi(c)] = sum_j w_j * (y_j(p0)+y_j(p1) + b2[e_j]) ----------------
__global__ __launch_bounds__(256) void combine_kernel(
    const __hip_bfloat16* __restrict__ yb, const float* __restrict__ b2,
    const int* __restrict__ base, const int* __restrict__ eidx,
    const float* __restrict__ ewgt, float* __restrict__ out, int T) {
    int t = blockIdx.x, tid = threadIdx.x;
    int v0 = eidx[2 * t], v1 = eidx[2 * t + 1];
    float w0 = ewgt[2 * t], w1 = ewgt[2 * t + 1];
    int e0 = v0 >> 16, e1 = v1 >> 16;
    size_t g0 = (size_t)base[e0] + (v0 & 0xffff);
    size_t g1 = (size_t)base[e1] + (v1 & 0xffff);
    int c = tid * 4;               // stored (permuted) col
    int blk = c >> 6;
    int tt = (c >> 2) & 15;
    size_t off2 = (size_t)2 * T * D_DIM;
    const short* ys = (const short*)yb;
    short4v a0 = *(const short4v*)(ys + g0 * D_DIM + c);
    short4v a1 = *(const short4v*)(ys + off2 + g0 * D_DIM + c);
    short4v c0 = *(const short4v*)(ys + g1 * D_DIM + c);
    short4v c1 = *(const short4v*)(ys + off2 + g1 * D_DIM + c);
    float s0[4] = { b2f(a0.x) + b2f(a1.x), b2f(a0.y) + b2f(a1.y),
                    b2f(a0.z) + b2f(a1.z), b2f(a0.w) + b2f(a1.w) };
    float s1[4] = { b2f(c0.x) + b2f(c1.x), b2f(c0.y) + b2f(c1.y),
                    b2f(c0.z) + b2f(c1.z), b2f(c0.w) + b2f(c1.w) };
    float* orow = out + (size_t)t * D_DIM;
#pragma unroll
    for (int s = 0; s < 4; ++s) {
        int oc = blk * 64 + s * 16 + tt;   // original col
        float o = w0 * (s0[s] + b2[(size_t)e0 * D_DIM + oc]) +
                  w1 * (s1[s] + b2[(size_t)e1 * D_DIM + oc]);
        orow[oc] = o;
    }
}

extern "C" void kernel_launch(void* const* d_in, const int* in_sizes, int n_in,
                              void* d_out, int out_size, void* d_ws, size_t ws_size,
                              hipStream_t stream) {
    const float* x  = (const float*)d_in[0];
    const float* Wg = (const float*)d_in[1];
    const float* W1 = (const float*)d_in[2];
    const float* b1 = (const float*)d_in[3];
    const float* W2 = (const float*)d_in[4];
    const float* b2 = (const float*)d_in[5];
    int T = in_sizes[0] / D_DIM;  // 8192

    char* p = (char*)d_ws;
    int* cnt   = (int*)p;
    int* base  = (int*)(p + 256);
    int* tok   = (int*)(p + 512);
    int* eidx  = (int*)(p + 512 + 4ll * E_NUM * T);
    float* ewgt = (float*)(p + 512 + 4ll * E_NUM * T + 8ll * T);
    int* epick = (int*)(p + 512 + 4ll * E_NUM * T + 16ll * T);
    char* pb = p + 512 + 4ll * E_NUM * T + 20ll * T;
    __hip_bfloat16* xb  = (__hip_bfloat16*)pb;
    __hip_bfloat16* w1t = xb + (size_t)T * D_DIM;
    __hip_bfloat16* w2t = w1t + (size_t)E_NUM * H_DIM * D_DIM;
    __hip_bfloat16* hb  = w2t + (size_t)E_NUM * H_DIM * D_DIM;
    // ybuf [2][2T][D] bf16 (67 MB) aliases xb+w1t (dead by gemm2 time).
    __hip_bfloat16* yb  = xb;

    hipMemsetAsync(cnt, 0, 256, stream);

    router_kernel<<<dim3((T + 3) / 4), 256, 0, stream>>>(x, Wg, xb, epick, ewgt, T);
    bucket_kernel<<<dim3(T / 128), 256, 0, stream>>>(epick, cnt, tok, eidx, T);
    prefix_kernel<<<1, 64, 0, stream>>>(cnt, base);
    transpose_both_kernel<<<dim3(2048, 1, E_NUM), dim3(32, 8), 0, stream>>>(W1, W2, w1t, w2t);
    gemm1_kernel<<<dim3(H_DIM / 256, T / 256, E_NUM), 512, 0, stream>>>(xb, w1t, b1, cnt, base, tok, hb, T);
    gemm2_kernel<<<dim3(D_DIM / 256, T / 256, E_NUM * 2), 512, 0, stream>>>(hb, w2t, cnt, base, yb, T);
    combine_kernel<<<T, 256, 0, stream>>>(yb, b2, base, eidx, ewgt, (float*)d_out, T);
}

// Round 3
// 787.494 us; speedup vs baseline: 1.1202x; 1.1202x over previous
//
#include <hip/hip_runtime.h>
#include <hip/hip_bf16.h>
#include <stdint.h>

#define D_DIM 1024
#define E_NUM 8
#define H_DIM 4096

typedef __attribute__((ext_vector_type(8))) short short8;
typedef __attribute__((ext_vector_type(4))) short short4v;
typedef __attribute__((ext_vector_type(4))) unsigned short ushort4v;
typedef __attribute__((ext_vector_type(4))) float f32x4;

#define GLOBAL_AS __attribute__((address_space(1)))
#define LDS_AS __attribute__((address_space(3)))

__device__ __forceinline__ void async_load16(const void* g, void* l) {
    __builtin_amdgcn_global_load_lds((GLOBAL_AS void*)g, (LDS_AS void*)l, 16, 0, 0);
}

// tanh-form gelu, branchless. |err| <= ~3e-4.
__device__ __forceinline__ float gelu_fast(float x) {
    float x3 = x * x * x;
    float z = 0.7978845608028654f * x + 0.0356774081363001f * x3;
    float u = __expf(-2.0f * fabsf(z));
    float t = __fdividef(1.0f - u, 1.0f + u);
    t = copysignf(t, z);
    return 0.5f * x * (1.0f + t);
}

__device__ __forceinline__ float b2f(short s) {
    union { float f; unsigned u; } x; x.u = ((unsigned)(unsigned short)s) << 16; return x.f;
}

__device__ __forceinline__ unsigned short f2b(float f) {
    union { __hip_bfloat16 h; unsigned short s; } u;
    u.h = __float2bfloat16(f);
    return u.s;
}

// ---------------- router: logits (fp64), softmax, top-2; NO global atomics; fused x->bf16 ----------------
__global__ __launch_bounds__(256) void router_kernel(
    const float* __restrict__ x, const float* __restrict__ Wg,
    __hip_bfloat16* __restrict__ xb, int* __restrict__ epick,
    float* __restrict__ ewgt, int T) {
    int gwave = (int)((blockIdx.x * 256 + threadIdx.x) >> 6);
    int lane = threadIdx.x & 63;
    if (gwave >= T) return;
    const float* xr = x + (size_t)gwave * D_DIM;
    double acc[E_NUM];
#pragma unroll
    for (int e = 0; e < E_NUM; ++e) acc[e] = 0.0;
#pragma unroll
    for (int i = 0; i < D_DIM / 64; ++i) {
        int d = i * 64 + lane;
        float xv = xr[d];
        xb[(size_t)gwave * D_DIM + d] = __float2bfloat16(xv);
        const float4* wgp = (const float4*)(Wg + (size_t)d * E_NUM);
        float4 wa = wgp[0], wb = wgp[1];
        double xd = (double)xv;
        acc[0] += xd * (double)wa.x; acc[1] += xd * (double)wa.y;
        acc[2] += xd * (double)wa.z; acc[3] += xd * (double)wa.w;
        acc[4] += xd * (double)wb.x; acc[5] += xd * (double)wb.y;
        acc[6] += xd * (double)wb.z; acc[7] += xd * (double)wb.w;
    }
#pragma unroll
    for (int s = 32; s > 0; s >>= 1) {
#pragma unroll
        for (int e = 0; e < E_NUM; ++e) acc[e] += __shfl_xor(acc[e], s);
    }
    double mx = acc[0];
#pragma unroll
    for (int e = 1; e < E_NUM; ++e) mx = fmax(mx, acc[e]);
    double p[E_NUM]; double sum = 0.0;
#pragma unroll
    for (int e = 0; e < E_NUM; ++e) { p[e] = exp(acc[e] - mx); sum += p[e]; }
    int i0 = 0;
#pragma unroll
    for (int e = 1; e < E_NUM; ++e) if (p[e] > p[i0]) i0 = e;
    int i1 = (i0 == 0) ? 1 : 0;
#pragma unroll
    for (int e = 0; e < E_NUM; ++e) if (e != i0 && p[e] > p[i1]) i1 = e;
    if (lane == 0) {
        epick[gwave] = i0 | (i1 << 8);
        ewgt[2 * gwave]     = (float)(p[i0] / sum);
        ewgt[2 * gwave + 1] = (float)(p[i1] / sum);
    }
}

// ---------------- bucket: block-aggregated scatter; 8 global atomics per block ----------------
__global__ __launch_bounds__(256) void bucket_kernel(
    const int* __restrict__ epick, int* __restrict__ cnt,
    int* __restrict__ tok, int* __restrict__ eidx, int T) {
    __shared__ int lcnt[E_NUM];
    __shared__ int gbase[E_NUM];
    int b = blockIdx.x, tid = threadIdx.x;
    if (tid < E_NUM) lcnt[tid] = 0;
    __syncthreads();
    int t = b * 128 + (tid >> 1);
    int j = tid & 1;
    int e = (epick[t] >> (j * 8)) & 0xff;
    int li = atomicAdd(&lcnt[e], 1);
    __syncthreads();
    if (tid < E_NUM) gbase[tid] = atomicAdd(&cnt[tid], lcnt[tid]);
    __syncthreads();
    int slot = gbase[e] + li;
    tok[e * T + slot] = t;
    eidx[2 * t + j] = (e << 16) | slot;
}

__global__ void prefix_kernel(const int* __restrict__ cnt, int* __restrict__ base) {
    if (threadIdx.x == 0) {
        int a = 0;
#pragma unroll
        for (int e = 0; e < E_NUM; ++e) { base[e] = a; a += cnt[e]; }
    }
}

// ---------------- unified W1/W2 transpose, 64x64 tiles, packed stores ----------------
// W1: [E][D][H] f32 -> w1t [E][H][D] bf16 (no perm).
// W2: [E][H][D] f32 -> w2t [E][D][H] bf16 with K(=H) perm pi(j)=(j&3)*16+(j>>2) per 64-block.
__global__ __launch_bounds__(256) void transpose_both_kernel(
    const float* __restrict__ W1, const float* __restrict__ W2,
    __hip_bfloat16* __restrict__ w1t, __hip_bfloat16* __restrict__ w2t) {
    __shared__ float tile[64][65];
    int e = blockIdx.z;
    int id = blockIdx.x;
    const float* src; unsigned short* dst; int R, C, r0, c0, perm;
    if (id < 1024) {  // W1: R=D rows, C=H cols
        R = D_DIM; C = H_DIM;
        r0 = (id >> 6) * 64; c0 = (id & 63) * 64;
        src = W1 + (size_t)e * D_DIM * H_DIM;
        dst = (unsigned short*)(w1t + (size_t)e * H_DIM * D_DIM);
        perm = 0;
    } else {          // W2: R=H rows, C=D cols
        id -= 1024;
        R = H_DIM; C = D_DIM;
        r0 = (id >> 4) * 64; c0 = (id & 15) * 64;
        src = W2 + (size_t)e * H_DIM * D_DIM;
        dst = (unsigned short*)(w2t + (size_t)e * D_DIM * H_DIM);
        perm = 1;
    }
    int tx = threadIdx.x, ty = threadIdx.y;  // 32 x 8
#pragma unroll
    for (int i = 0; i < 8; ++i) {
        int j = ty + i * 8;
        int sr = perm ? ((j & 3) * 16 + (j >> 2)) : j;
        float2 v = *(const float2*)(src + (size_t)(r0 + sr) * C + c0 + 2 * tx);
        tile[j][2 * tx] = v.x; tile[j][2 * tx + 1] = v.y;
    }
    __syncthreads();
#pragma unroll
    for (int i = 0; i < 8; ++i) {
        int cc = ty + i * 8;
        unsigned pk = (unsigned)f2b(tile[2 * tx][cc]) | ((unsigned)f2b(tile[2 * tx + 1][cc]) << 16);
        *(unsigned*)(dst + (size_t)(c0 + cc) * R + r0 + 2 * tx) = pk;
    }
}

// ====================== 256x256 fine-phase (m201-style) GEMMs ======================
// Round-2 post-mortem: coarse 1-phase-per-tile + counted vmcnt REGRESSED
// (MfmaUtil 30->22) — reproduces m196's "coarse split without fine interleave
// hurts". This version ports the m201 8-phase density onto the proven BK=32
// conflict-free chunk-swizzle layout:
//   per K-tile (BK=32), TWO phases, each = { 8/4 ds_read_b128 + 2
//   global_load_lds -> s_barrier -> setprio(1) -> 16 MFMA -> setprio(0) ->
//   s_barrier }.  Same per-phase density as m201 (16 MFMA, <=8 reads,
//   2 stage loads, 2 barriers).
// vmcnt(8) ONCE per tile (end of phase B), never 0 in the main loop: 4-deep
// buffers, tiles t+2,t+3 (8 loads/thread) stay in flight across barriers.
// LDS read offsets hoisted out of the K-loop (K-invariant); loop unrolled x4
// so buffer bases are compile-time constants.
// LDS swizzle: proven BK=32 K-chunk scheme (row r chunk k at chunk
// r*4 + (k ^ ((r>>1)&3)); writer pre-swizzles the global source chunk,
// global_load_lds dest stays linear). Measured 0 bank conflicts.

#define MOE_TILE(BI, KK, DO_STAGE, VM)                                         \
    {                                                                          \
        const char* pa_ = (const char*)sA + (BI) * 16384;                      \
        const char* pb_ = (const char*)sB + (BI) * 16384;                      \
        short8 aF[4], bF[4];                                                   \
        _Pragma("unroll")                                                      \
        for (int n = 0; n < 4; ++n) bF[n] = *(const short8*)(pb_ + offB[n]);   \
        _Pragma("unroll")                                                      \
        for (int m = 0; m < 4; ++m) aF[m] = *(const short8*)(pa_ + offA[m]);   \
        if (DO_STAGE) {                                                        \
            char* dA_ = stA + (((BI) + 3) & 3) * 16384;                        \
            async_load16(gA0 + (KK), dA_);                                     \
            async_load16(gA1 + (KK), dA_ + 1024);                              \
        }                                                                      \
        __builtin_amdgcn_s_barrier();                                          \
        __builtin_amdgcn_s_setprio(1);                                         \
        _Pragma("unroll")                                                      \
        for (int m = 0; m < 4; ++m)                                            \
            _Pragma("unroll")                                                  \
            for (int n = 0; n < 4; ++n)                                        \
                acc[m][n] = __builtin_amdgcn_mfma_f32_16x16x32_bf16(           \
                    aF[m], bF[n], acc[m][n], 0, 0, 0);                         \
        __builtin_amdgcn_s_setprio(0);                                         \
        __builtin_amdgcn_s_barrier();                                          \
        _Pragma("unroll")                                                      \
        for (int m = 0; m < 4; ++m) aF[m] = *(const short8*)(pa_ + offA[4 + m]); \
        if (DO_STAGE) {                                                        \
            char* dB_ = stB + (((BI) + 3) & 3) * 16384;                        \
            async_load16(gB0 + (KK), dB_);                                     \
            async_load16(gB1 + (KK), dB_ + 1024);                              \
        }                                                                      \
        if ((VM) == 8) asm volatile("s_waitcnt vmcnt(8)" ::: "memory");        \
        else if ((VM) == 4) asm volatile("s_waitcnt vmcnt(4)" ::: "memory");   \
        else if ((VM) == 0) asm volatile("s_waitcnt vmcnt(0)" ::: "memory");   \
        __builtin_amdgcn_s_barrier();                                          \
        __builtin_amdgcn_s_setprio(1);                                         \
        _Pragma("unroll")                                                      \
        for (int m = 0; m < 4; ++m)                                            \
            _Pragma("unroll")                                                  \
            for (int n = 0; n < 4; ++n)                                        \
                acc[4 + m][n] = __builtin_amdgcn_mfma_f32_16x16x32_bf16(       \
                    aF[m], bF[n], acc[4 + m][n], 0, 0, 0);                     \
        __builtin_amdgcn_s_setprio(0);                                         \
        __builtin_amdgcn_s_barrier();                                          \
    }

// ---------------- GEMM1: h[slot, perm(col)] = gelu(x[tok] @ W1[e] + b1[e]) ----------------
__global__ __launch_bounds__(512) void gemm1_kernel(
    const __hip_bfloat16* __restrict__ xb,   // [T][D]
    const __hip_bfloat16* __restrict__ w1t,  // [E][H][D] (B^T)
    const float* __restrict__ b1,            // [E][H]
    const int* __restrict__ cnt, const int* __restrict__ base,
    const int* __restrict__ tok,
    __hip_bfloat16* __restrict__ hbuf,       // [2T][H] (N-permuted)
    int T) {
    int e = blockIdx.z;
    int M = cnt[e];
    int m0 = blockIdx.y * 256;
    if (m0 >= M) return;
    int n0 = blockIdx.x * 256;
    const __hip_bfloat16* Bp = w1t + (size_t)e * H_DIM * D_DIM;

    __shared__ __align__(16) short sA[4][256 * 32];
    __shared__ __align__(16) short sB[4][256 * 32];
    __shared__ float sBias[256];

    int tid = threadIdx.x;
    int w = tid >> 6, lane = tid & 63;
    int wm = w >> 2, wn = w & 3;
    int q = lane >> 4, l4 = lane & 15;

    if (tid < 256) sBias[tid] = b1[e * H_DIM + n0 + tid];

    int kswz = ((lane & 3) ^ ((lane >> 3) & 3)) << 3;  // pre-swizzled global chunk
    int r0 = w * 32 + (lane >> 2);
    int r1 = r0 + 16;
    int tA0 = tok[e * T + min(m0 + r0, M - 1)];
    int tA1 = tok[e * T + min(m0 + r1, M - 1)];
    const __hip_bfloat16* gA0 = xb + (size_t)tA0 * D_DIM + kswz;
    const __hip_bfloat16* gA1 = xb + (size_t)tA1 * D_DIM + kswz;
    const __hip_bfloat16* gB0 = Bp + (size_t)(n0 + r0) * D_DIM + kswz;
    const __hip_bfloat16* gB1 = Bp + (size_t)(n0 + r1) * D_DIM + kswz;
    char* stA = (char*)sA + w * 2048;  // wave-uniform dest; HW adds lane*16
    char* stB = (char*)sB + w * 2048;

    // K-invariant LDS read offsets (within one 16KB buffer)
    int offA[8], offB[4];
#pragma unroll
    for (int m = 0; m < 8; ++m) {
        int ra = wm * 128 + m * 16 + l4;
        offA[m] = ra * 64 + ((q ^ ((ra >> 1) & 3)) << 4);
    }
#pragma unroll
    for (int n = 0; n < 4; ++n) {
        int rb = wn * 64 + n * 16 + l4;
        offB[n] = rb * 64 + ((q ^ ((rb >> 1) & 3)) << 4);
    }

    f32x4 acc[8][4];
#pragma unroll
    for (int a = 0; a < 8; ++a)
#pragma unroll
        for (int b = 0; b < 4; ++b) acc[a][b] = (f32x4){0.f, 0.f, 0.f, 0.f};

    auto stage = [&](int tt) {
        int kk = tt * 32;
        char* la = stA + (tt & 3) * 16384;
        char* lb = stB + (tt & 3) * 16384;
        async_load16(gA0 + kk, la);
        async_load16(gA1 + kk, la + 1024);
        async_load16(gB0 + kk, lb);
        async_load16(gB1 + kk, lb + 1024);
    };

    const int nt = D_DIM / 32;  // 32
    asm volatile("s_waitcnt vmcnt(0)" ::: "memory");  // drain pre-pipeline loads
    stage(0); stage(1); stage(2);
    asm volatile("s_waitcnt vmcnt(8)" ::: "memory");
    __builtin_amdgcn_s_barrier();
    MOE_TILE(0, 3 * 32, 1, 8);                 // t = 0
    for (int i = 0; i < (nt - 4) / 4; ++i) {   // t = 1 .. nt-4, groups of 4
        int tb = 1 + i * 4;
        MOE_TILE(1, (tb + 3) * 32, 1, 8);
        MOE_TILE(2, (tb + 4) * 32, 1, 8);
        MOE_TILE(3, (tb + 5) * 32, 1, 8);
        MOE_TILE(0, (tb + 6) * 32, 1, 8);
    }
    MOE_TILE(1, 0, 0, 4);                      // t = nt-3
    MOE_TILE(2, 0, 0, 0);                      // t = nt-2
    MOE_TILE(3, 0, 0, -1);                     // t = nt-1

    int sb = base[e];
    unsigned short* hs = (unsigned short*)hbuf;
#pragma unroll
    for (int m = 0; m < 8; ++m) {
        int rbase = wm * 128 + m * 16 + q * 4;
#pragma unroll
        for (int i = 0; i < 4; ++i) {
            int row = m0 + rbase + i;
            if (row < M) {
                size_t hrow = (size_t)(sb + row) * H_DIM;
                ushort4v pk;
#pragma unroll
                for (int n = 0; n < 4; ++n) {
                    float v = acc[m][n][i] + sBias[wn * 64 + n * 16 + l4];
                    pk[n] = f2b(gelu_fast(v));
                }
                *(ushort4v*)(hs + hrow + n0 + wn * 64 + l4 * 4) = pk;
            }
        }
    }
}

// ---------------- GEMM2 (split-K=2): ybuf[kc][slot, perm(col)] = partial(h @ W2[e]) ----------------
__global__ __launch_bounds__(512) void gemm2_kernel(
    const __hip_bfloat16* __restrict__ hbuf, // [2T][H] (K-permuted, matches w2t)
    const __hip_bfloat16* __restrict__ w2t,  // [E][D][H] (B^T, K-permuted)
    const int* __restrict__ cnt, const int* __restrict__ base,
    __hip_bfloat16* __restrict__ ybuf,       // [2][2T][D] (N-permuted)
    int T) {
    int e = blockIdx.z >> 1;
    int kc = blockIdx.z & 1;
    int M = cnt[e];
    int m0 = blockIdx.y * 256;
    if (m0 >= M) return;
    int n0 = blockIdx.x * 256;
    int sb = base[e];
    const __hip_bfloat16* Bp = w2t + (size_t)e * D_DIM * H_DIM;

    __shared__ __align__(16) short sA[4][256 * 32];
    __shared__ __align__(16) short sB[4][256 * 32];

    int tid = threadIdx.x;
    int w = tid >> 6, lane = tid & 63;
    int wm = w >> 2, wn = w & 3;
    int q = lane >> 4, l4 = lane & 15;

    int kswz = ((lane & 3) ^ ((lane >> 3) & 3)) << 3;
    int r0 = w * 32 + (lane >> 2);
    int r1 = r0 + 16;
    int k0 = kc * (H_DIM / 2);
    const __hip_bfloat16* gA0 = hbuf + (size_t)(sb + min(m0 + r0, M - 1)) * H_DIM + k0 + kswz;
    const __hip_bfloat16* gA1 = hbuf + (size_t)(sb + min(m0 + r1, M - 1)) * H_DIM + k0 + kswz;
    const __hip_bfloat16* gB0 = Bp + (size_t)(n0 + r0) * H_DIM + k0 + kswz;
    const __hip_bfloat16* gB1 = Bp + (size_t)(n0 + r1) * H_DIM + k0 + kswz;
    char* stA = (char*)sA + w * 2048;
    char* stB = (char*)sB + w * 2048;

    int offA[8], offB[4];
#pragma unroll
    for (int m = 0; m < 8; ++m) {
        int ra = wm * 128 + m * 16 + l4;
        offA[m] = ra * 64 + ((q ^ ((ra >> 1) & 3)) << 4);
    }
#pragma unroll
    for (int n = 0; n < 4; ++n) {
        int rb = wn * 64 + n * 16 + l4;
        offB[n] = rb * 64 + ((q ^ ((rb >> 1) & 3)) << 4);
    }

    f32x4 acc[8][4];
#pragma unroll
    for (int a = 0; a < 8; ++a)
#pragma unroll
        for (int b = 0; b < 4; ++b) acc[a][b] = (f32x4){0.f, 0.f, 0.f, 0.f};

    auto stage = [&](int tt) {
        int kk = tt * 32;
        char* la = stA + (tt & 3) * 16384;
        char* lb = stB + (tt & 3) * 16384;
        async_load16(gA0 + kk, la);
        async_load16(gA1 + kk, la + 1024);
        async_load16(gB0 + kk, lb);
        async_load16(gB1 + kk, lb + 1024);
    };

    const int nt = (H_DIM / 2) / 32;  // 64
    asm volatile("s_waitcnt vmcnt(0)" ::: "memory");
    stage(0); stage(1); stage(2);
    asm volatile("s_waitcnt vmcnt(8)" ::: "memory");
    __builtin_amdgcn_s_barrier();
    MOE_TILE(0, 3 * 32, 1, 8);                 // t = 0
    for (int i = 0; i < (nt - 4) / 4; ++i) {   // t = 1 .. nt-4, groups of 4
        int tb = 1 + i * 4;
        MOE_TILE(1, (tb + 3) * 32, 1, 8);
        MOE_TILE(2, (tb + 4) * 32, 1, 8);
        MOE_TILE(3, (tb + 5) * 32, 1, 8);
        MOE_TILE(0, (tb + 6) * 32, 1, 8);
    }
    MOE_TILE(1, 0, 0, 4);                      // t = nt-3
    MOE_TILE(2, 0, 0, 0);                      // t = nt-2
    MOE_TILE(3, 0, 0, -1);                     // t = nt-1

    size_t ybase = (size_t)kc * 2 * T;
    unsigned short* ys = (unsigned short*)ybuf;
#pragma unroll
    for (int m = 0; m < 8; ++m) {
        int rbase = wm * 128 + m * 16 + q * 4;
#pragma unroll
        for (int i = 0; i < 4; ++i) {
            int row = m0 + rbase + i;
            if (row < M) {
                size_t yrow = (ybase + sb + row) * D_DIM;
                ushort4v pk;
#pragma unroll
                for (int n = 0; n < 4; ++n) pk[n] = f2b(acc[m][n][i]);
                *(ushort4v*)(ys + yrow + n0 + wn * 64 + l4 * 4) = pk;
            }
        }
    }
}

// ---------------- combine: out[t, pi(c)] = sum_j w_j * (y_j(p0)+y_j(p1) + b2[e_j]) ----------------
__global__ __launch_bounds__(256) void combine_kernel(
    const __hip_bfloat16* __restrict__ yb, const float* __restrict__ b2,
    const int* __restrict__ base, const int* __restrict__ eidx,
    const float* __restrict__ ewgt, float* __restrict__ out, int T) {
    int t = blockIdx.x, tid = threadIdx.x;
    int v0 = eidx[2 * t], v1 = eidx[2 * t + 1];
    float w0 = ewgt[2 * t], w1 = ewgt[2 * t + 1];
    int e0 = v0 >> 16, e1 = v1 >> 16;
    size_t g0 = (size_t)base[e0] + (v0 & 0xffff);
    size_t g1 = (size_t)base[e1] + (v1 & 0xffff);
    int c = tid * 4;               // stored (permuted) col
    int blk = c >> 6;
    int tt = (c >> 2) & 15;
    size_t off2 = (size_t)2 * T * D_DIM;
    const short* ys = (const short*)yb;
    short4v a0 = *(const short4v*)(ys + g0 * D_DIM + c);
    short4v a1 = *(const short4v*)(ys + off2 + g0 * D_DIM + c);
    short4v c0 = *(const short4v*)(ys + g1 * D_DIM + c);
    short4v c1 = *(const short4v*)(ys + off2 + g1 * D_DIM + c);
    float s0[4] = { b2f(a0.x) + b2f(a1.x), b2f(a0.y) + b2f(a1.y),
                    b2f(a0.z) + b2f(a1.z), b2f(a0.w) + b2f(a1.w) };
    float s1[4] = { b2f(c0.x) + b2f(c1.x), b2f(c0.y) + b2f(c1.y),
                    b2f(c0.z) + b2f(c1.z), b2f(c0.w) + b2f(c1.w) };
    float* orow = out + (size_t)t * D_DIM;
#pragma unroll
    for (int s = 0; s < 4; ++s) {
        int oc = blk * 64 + s * 16 + tt;   // original col
        float o = w0 * (s0[s] + b2[(size_t)e0 * D_DIM + oc]) +
                  w1 * (s1[s] + b2[(size_t)e1 * D_DIM + oc]);
        orow[oc] = o;
    }
}

extern "C" void kernel_launch(void* const* d_in, const int* in_sizes, int n_in,
                              void* d_out, int out_size, void* d_ws, size_t ws_size,
                              hipStream_t stream) {
    const float* x  = (const float*)d_in[0];
    const float* Wg = (const float*)d_in[1];
    const float* W1 = (const float*)d_in[2];
    const float* b1 = (const float*)d_in[3];
    const float* W2 = (const float*)d_in[4];
    const float* b2 = (const float*)d_in[5];
    int T = in_sizes[0] / D_DIM;  // 8192

    char* p = (char*)d_ws;
    int* cnt   = (int*)p;
    int* base  = (int*)(p + 256);
    int* tok   = (int*)(p + 512);
    int* eidx  = (int*)(p + 512 + 4ll * E_NUM * T);
    float* ewgt = (float*)(p + 512 + 4ll * E_NUM * T + 8ll * T);
    int* epick = (int*)(p + 512 + 4ll * E_NUM * T + 16ll * T);
    char* pb = p + 512 + 4ll * E_NUM * T + 20ll * T;
    __hip_bfloat16* xb  = (__hip_bfloat16*)pb;
    __hip_bfloat16* w1t = xb + (size_t)T * D_DIM;
    __hip_bfloat16* w2t = w1t + (size_t)E_NUM * H_DIM * D_DIM;
    __hip_bfloat16* hb  = w2t + (size_t)E_NUM * H_DIM * D_DIM;
    // ybuf [2][2T][D] bf16 (67 MB) aliases xb+w1t (dead by gemm2 time).
    __hip_bfloat16* yb  = xb;

    hipMemsetAsync(cnt, 0, 256, stream);

    router_kernel<<<dim3((T + 3) / 4), 256, 0, stream>>>(x, Wg, xb, epick, ewgt, T);
    bucket_kernel<<<dim3(T / 128), 256, 0, stream>>>(epick, cnt, tok, eidx, T);
    prefix_kernel<<<1, 64, 0, stream>>>(cnt, base);
    transpose_both_kernel<<<dim3(2048, 1, E_NUM), dim3(32, 8), 0, stream>>>(W1, W2, w1t, w2t);
    gemm1_kernel<<<dim3(H_DIM / 256, T / 256, E_NUM), 512, 0, stream>>>(xb, w1t, b1, cnt, base, tok, hb, T);
    gemm2_kernel<<<dim3(D_DIM / 256, T / 256, E_NUM * 2), 512, 0, stream>>>(hb, w2t, cnt, base, yb, T);
    combine_kernel<<<T, 256, 0, stream>>>(yb, b2, base, eidx, ewgt, (float*)d_out, T);
}

// Round 4
// 746.632 us; speedup vs baseline: 1.1815x; 1.0547x over previous
//
#include <hip/hip_runtime.h>
#include <hip/hip_bf16.h>
#include <stdint.h>

#define D_DIM 1024
#define E_NUM 8
#define H_DIM 4096

typedef __attribute__((ext_vector_type(8))) short short8;
typedef __attribute__((ext_vector_type(4))) short short4v;
typedef __attribute__((ext_vector_type(4))) unsigned short ushort4v;
typedef __attribute__((ext_vector_type(4))) float f32x4;

#define GLOBAL_AS __attribute__((address_space(1)))
#define LDS_AS __attribute__((address_space(3)))

__device__ __forceinline__ void async_load16(const void* g, void* l) {
    __builtin_amdgcn_global_load_lds((GLOBAL_AS void*)g, (LDS_AS void*)l, 16, 0, 0);
}

// tanh-form gelu, branchless. |err| <= ~3e-4.
__device__ __forceinline__ float gelu_fast(float x) {
    float x3 = x * x * x;
    float z = 0.7978845608028654f * x + 0.0356774081363001f * x3;
    float u = __expf(-2.0f * fabsf(z));
    float t = __fdividef(1.0f - u, 1.0f + u);
    t = copysignf(t, z);
    return 0.5f * x * (1.0f + t);
}

__device__ __forceinline__ float b2f(short s) {
    union { float f; unsigned u; } x; x.u = ((unsigned)(unsigned short)s) << 16; return x.f;
}

__device__ __forceinline__ unsigned short f2b(float f) {
    union { __hip_bfloat16 h; unsigned short s; } u;
    u.h = __float2bfloat16(f);
    return u.s;
}

// ---------------- router: logits (fp64), softmax, top-2; NO global atomics; fused x->bf16 ----------------
__global__ __launch_bounds__(256) void router_kernel(
    const float* __restrict__ x, const float* __restrict__ Wg,
    __hip_bfloat16* __restrict__ xb, int* __restrict__ epick,
    float* __restrict__ ewgt, int T) {
    int gwave = (int)((blockIdx.x * 256 + threadIdx.x) >> 6);
    int lane = threadIdx.x & 63;
    if (gwave >= T) return;
    const float* xr = x + (size_t)gwave * D_DIM;
    double acc[E_NUM];
#pragma unroll
    for (int e = 0; e < E_NUM; ++e) acc[e] = 0.0;
#pragma unroll
    for (int i = 0; i < D_DIM / 64; ++i) {
        int d = i * 64 + lane;
        float xv = xr[d];
        xb[(size_t)gwave * D_DIM + d] = __float2bfloat16(xv);
        const float4* wgp = (const float4*)(Wg + (size_t)d * E_NUM);
        float4 wa = wgp[0], wb = wgp[1];
        double xd = (double)xv;
        acc[0] += xd * (double)wa.x; acc[1] += xd * (double)wa.y;
        acc[2] += xd * (double)wa.z; acc[3] += xd * (double)wa.w;
        acc[4] += xd * (double)wb.x; acc[5] += xd * (double)wb.y;
        acc[6] += xd * (double)wb.z; acc[7] += xd * (double)wb.w;
    }
#pragma unroll
    for (int s = 32; s > 0; s >>= 1) {
#pragma unroll
        for (int e = 0; e < E_NUM; ++e) acc[e] += __shfl_xor(acc[e], s);
    }
    double mx = acc[0];
#pragma unroll
    for (int e = 1; e < E_NUM; ++e) mx = fmax(mx, acc[e]);
    double p[E_NUM]; double sum = 0.0;
#pragma unroll
    for (int e = 0; e < E_NUM; ++e) { p[e] = exp(acc[e] - mx); sum += p[e]; }
    int i0 = 0;
#pragma unroll
    for (int e = 1; e < E_NUM; ++e) if (p[e] > p[i0]) i0 = e;
    int i1 = (i0 == 0) ? 1 : 0;
#pragma unroll
    for (int e = 0; e < E_NUM; ++e) if (e != i0 && p[e] > p[i1]) i1 = e;
    if (lane == 0) {
        epick[gwave] = i0 | (i1 << 8);
        ewgt[2 * gwave]     = (float)(p[i0] / sum);
        ewgt[2 * gwave + 1] = (float)(p[i1] / sum);
    }
}

// ---------------- bucket: block-aggregated scatter; 8 global atomics per block ----------------
__global__ __launch_bounds__(256) void bucket_kernel(
    const int* __restrict__ epick, int* __restrict__ cnt,
    int* __restrict__ tok, int* __restrict__ eidx, int T) {
    __shared__ int lcnt[E_NUM];
    __shared__ int gbase[E_NUM];
    int b = blockIdx.x, tid = threadIdx.x;
    if (tid < E_NUM) lcnt[tid] = 0;
    __syncthreads();
    int t = b * 128 + (tid >> 1);
    int j = tid & 1;
    int e = (epick[t] >> (j * 8)) & 0xff;
    int li = atomicAdd(&lcnt[e], 1);
    __syncthreads();
    if (tid < E_NUM) gbase[tid] = atomicAdd(&cnt[tid], lcnt[tid]);
    __syncthreads();
    int slot = gbase[e] + li;
    tok[e * T + slot] = t;
    eidx[2 * t + j] = (e << 16) | slot;
}

__global__ void prefix_kernel(const int* __restrict__ cnt, int* __restrict__ base) {
    if (threadIdx.x == 0) {
        int a = 0;
#pragma unroll
        for (int e = 0; e < E_NUM; ++e) { base[e] = a; a += cnt[e]; }
    }
}

// ---------------- unified W1/W2 transpose, 64x64 tiles, packed stores ----------------
// W1: [E][D][H] f32 -> w1t [E][H][D] bf16 (no perm).
// W2: [E][H][D] f32 -> w2t [E][D][H] bf16 with K(=H) perm pi(j)=(j&3)*16+(j>>2) per 64-block.
__global__ __launch_bounds__(256) void transpose_both_kernel(
    const float* __restrict__ W1, const float* __restrict__ W2,
    __hip_bfloat16* __restrict__ w1t, __hip_bfloat16* __restrict__ w2t) {
    __shared__ float tile[64][65];
    int e = blockIdx.z;
    int id = blockIdx.x;
    const float* src; unsigned short* dst; int R, C, r0, c0, perm;
    if (id < 1024) {  // W1: R=D rows, C=H cols
        R = D_DIM; C = H_DIM;
        r0 = (id >> 6) * 64; c0 = (id & 63) * 64;
        src = W1 + (size_t)e * D_DIM * H_DIM;
        dst = (unsigned short*)(w1t + (size_t)e * H_DIM * D_DIM);
        perm = 0;
    } else {          // W2: R=H rows, C=D cols
        id -= 1024;
        R = H_DIM; C = D_DIM;
        r0 = (id >> 4) * 64; c0 = (id & 15) * 64;
        src = W2 + (size_t)e * H_DIM * D_DIM;
        dst = (unsigned short*)(w2t + (size_t)e * D_DIM * H_DIM);
        perm = 1;
    }
    int tx = threadIdx.x, ty = threadIdx.y;  // 32 x 8
#pragma unroll
    for (int i = 0; i < 8; ++i) {
        int j = ty + i * 8;
        int sr = perm ? ((j & 3) * 16 + (j >> 2)) : j;
        float2 v = *(const float2*)(src + (size_t)(r0 + sr) * C + c0 + 2 * tx);
        tile[j][2 * tx] = v.x; tile[j][2 * tx + 1] = v.y;
    }
    __syncthreads();
#pragma unroll
    for (int i = 0; i < 8; ++i) {
        int cc = ty + i * 8;
        unsigned pk = (unsigned)f2b(tile[2 * tx][cc]) | ((unsigned)f2b(tile[2 * tx + 1][cc]) << 16);
        *(unsigned*)(dst + (size_t)(c0 + cc) * R + r0 + 2 * tx) = pk;
    }
}

// ====================== GEMMs: proven round-0 128x128 structure + T1 XCD swizzle ======================
// Rounds 2-3 post-mortem: both 256x256 counted-vmcnt schedules (coarse and
// m201-style fine-phase) REGRESSED vs this structure (282/242 vs 210 us;
// MfmaUtil 22/25.6 vs 30) — dropping to 1 block/CU killed the implicit
// 3-block/CU wave-level overlap and the ported schedule did not reproduce
// m201's intra-block overlap. Reverted verbatim; the only change is T1:
// XCD-chunked blockIdx swizzle, x-major work layout per expert plane, so
// each XCD's L2 keeps a few B-panels + the expert's A slab instead of
// round-robin spreading every panel across all 8 L2s. Per-plane grids are
// multiples of 8 (2048 / 512) and plane offsets are 0 mod 8 -> bijective,
// XCD-stable (m204 rule).
// LDS K-chunk swizzle (BK=32, 64 B rows = 4 chunks): row r chunk k stored at
// chunk r*4 + (k ^ ((r>>1)&3)). Writer (async, dest = base+lane*16): lane
// sources global chunk (lane&3)^((lane>>3)&3) of row (lane>>2). Reader: chunk
// q of row ra at byte ra*64 + ((q ^ ((ra >> 1) & 3))<<4). Conflict-free (measured:
// SQ_LDS_BANK_CONFLICT 0). Keep BK=32 (BK=64 regressed: occupancy 41->21).

// ---------------- GEMM1: h[slot, perm(col)] = gelu(x[tok] @ W1[e] + b1[e]), BK=32 ----------------
__global__ __launch_bounds__(256) void gemm1_kernel(
    const __hip_bfloat16* __restrict__ xb,   // [T][D]
    const __hip_bfloat16* __restrict__ w1t,  // [E][H][D] (B^T)
    const float* __restrict__ b1,            // [E][H]
    const int* __restrict__ cnt, const int* __restrict__ base,
    const int* __restrict__ tok,
    __hip_bfloat16* __restrict__ hbuf,       // [2T][H] (N-permuted)
    int T) {
    int e = blockIdx.z;
    int M = cnt[e];
    // T1 swizzle: GX=32 B-panels, GY=T/128 rows; work id x-major so each
    // XCD chunk = 4 consecutive B-panels (4x256KB in L2) x all A rows.
    int GY = T >> 7;                              // 64
    int hw = blockIdx.y * (H_DIM / 128) + blockIdx.x;
    int work = (hw & 7) * (((H_DIM / 128) * GY) >> 3) + (hw >> 3);
    int bx = work / GY, by = work - bx * GY;
    int m0 = by * 128;
    if (m0 >= M) return;
    int n0 = bx * 128;
    const __hip_bfloat16* Bp = w1t + (size_t)e * H_DIM * D_DIM;

    __shared__ __align__(16) short sA[128 * 32];
    __shared__ __align__(16) short sB[128 * 32];
    __shared__ float sBias[128];
    char* sAc = (char*)sA; char* sBc = (char*)sB;

    int tid = threadIdx.x;
    int w = tid >> 6, lane = tid & 63;
    int wm = w >> 1, wn = w & 1;
    int q = lane >> 4, l4 = lane & 15;

    if (tid < 128) sBias[tid] = b1[e * H_DIM + n0 + tid];

    int kswz = ((lane & 3) ^ ((lane >> 3) & 3)) << 3;  // swizzled element offset
    int r0 = w * 32 + (lane >> 2);
    int r1 = r0 + 16;
    int tA0 = tok[e * T + min(m0 + r0, M - 1)];
    int tA1 = tok[e * T + min(m0 + r1, M - 1)];
    const __hip_bfloat16* gA0 = xb + (size_t)tA0 * D_DIM + kswz;
    const __hip_bfloat16* gA1 = xb + (size_t)tA1 * D_DIM + kswz;
    const __hip_bfloat16* gB0 = Bp + (size_t)(n0 + r0) * D_DIM + kswz;
    const __hip_bfloat16* gB1 = Bp + (size_t)(n0 + r1) * D_DIM + kswz;
    char* lA0 = sAc + w * 2048 + lane * 16;
    char* lB0 = sBc + w * 2048 + lane * 16;
    char* lA1 = sAc + w * 2048 + 1024;  // wave's second segment base
    char* lB1 = sBc + w * 2048 + 1024;

    f32x4 acc[4][4];
#pragma unroll
    for (int a = 0; a < 4; ++a)
#pragma unroll
        for (int b = 0; b < 4; ++b) acc[a][b] = (f32x4){0.f, 0.f, 0.f, 0.f};

    for (int kk = 0; kk < D_DIM; kk += 32) {
        async_load16(gA0 + kk, lA0);
        async_load16(gA1 + kk, lA1);
        async_load16(gB0 + kk, lB0);
        async_load16(gB1 + kk, lB1);
        __syncthreads();
        short8 aF[4], bF[4];
#pragma unroll
        for (int t = 0; t < 4; ++t) {
            int ra = wm * 64 + t * 16 + l4;
            aF[t] = *(const short8*)(sAc + ra * 64 + ((q ^ ((ra >> 1) & 3)) << 4));
            int rb = wn * 64 + t * 16 + l4;
            bF[t] = *(const short8*)(sBc + rb * 64 + ((q ^ ((rb >> 1) & 3)) << 4));
        }
#pragma unroll
        for (int tm = 0; tm < 4; ++tm)
#pragma unroll
            for (int tn = 0; tn < 4; ++tn)
                acc[tm][tn] = __builtin_amdgcn_mfma_f32_16x16x32_bf16(aF[tm], bF[tn], acc[tm][tn], 0, 0, 0);
        __syncthreads();
    }

    int sb = base[e];
    unsigned short* hs = (unsigned short*)hbuf;
#pragma unroll
    for (int tm = 0; tm < 4; ++tm) {
        int rbase = wm * 64 + tm * 16 + q * 4;
#pragma unroll
        for (int i = 0; i < 4; ++i) {
            int row = m0 + rbase + i;
            if (row < M) {
                size_t hrow = (size_t)(sb + row) * H_DIM;
                ushort4v pk;
#pragma unroll
                for (int tn = 0; tn < 4; ++tn) {
                    float v = acc[tm][tn][i] + sBias[wn * 64 + tn * 16 + l4];
                    pk[tn] = f2b(gelu_fast(v));
                }
                *(ushort4v*)(hs + hrow + n0 + wn * 64 + l4 * 4) = pk;
            }
        }
    }
}

// ---------------- GEMM2 (split-K=2, BK=32): ybuf[kc][slot, perm(col)] = partial(h @ W2[e]) ----------------
__global__ __launch_bounds__(256) void gemm2_kernel(
    const __hip_bfloat16* __restrict__ hbuf, // [2T][H] (K-permuted, matches w2t)
    const __hip_bfloat16* __restrict__ w2t,  // [E][D][H] (B^T, K-permuted)
    const int* __restrict__ cnt, const int* __restrict__ base,
    __hip_bfloat16* __restrict__ ybuf,       // [2][2T][D] (N-permuted)
    int T) {
    int e = blockIdx.z >> 1;
    int kc = blockIdx.z & 1;
    int M = cnt[e];
    // T1 swizzle: GX=8 B-panels (1MB each), GY=T/128; each XCD chunk = 1
    // B-panel x all A rows.
    int GY = T >> 7;                              // 64
    int hw = blockIdx.y * (D_DIM / 128) + blockIdx.x;
    int work = (hw & 7) * (((D_DIM / 128) * GY) >> 3) + (hw >> 3);
    int bx = work / GY, by = work - bx * GY;
    int m0 = by * 128;
    if (m0 >= M) return;
    int n0 = bx * 128;
    int sb = base[e];
    const __hip_bfloat16* Bp = w2t + (size_t)e * D_DIM * H_DIM;

    __shared__ __align__(16) short sA[128 * 32];
    __shared__ __align__(16) short sB[128 * 32];
    char* sAc = (char*)sA; char* sBc = (char*)sB;

    int tid = threadIdx.x;
    int w = tid >> 6, lane = tid & 63;
    int wm = w >> 1, wn = w & 1;
    int q = lane >> 4, l4 = lane & 15;

    int kswz = ((lane & 3) ^ ((lane >> 3) & 3)) << 3;
    int r0 = w * 32 + (lane >> 2);
    int r1 = r0 + 16;
    const __hip_bfloat16* gA0 = hbuf + (size_t)(sb + min(m0 + r0, M - 1)) * H_DIM + kswz;
    const __hip_bfloat16* gA1 = hbuf + (size_t)(sb + min(m0 + r1, M - 1)) * H_DIM + kswz;
    const __hip_bfloat16* gB0 = Bp + (size_t)(n0 + r0) * H_DIM + kswz;
    const __hip_bfloat16* gB1 = Bp + (size_t)(n0 + r1) * H_DIM + kswz;
    char* lA0 = sAc + w * 2048 + lane * 16;
    char* lB0 = sBc + w * 2048 + lane * 16;
    char* lA1 = sAc + w * 2048 + 1024;
    char* lB1 = sBc + w * 2048 + 1024;

    f32x4 acc[4][4];
#pragma unroll
    for (int a = 0; a < 4; ++a)
#pragma unroll
        for (int b = 0; b < 4; ++b) acc[a][b] = (f32x4){0.f, 0.f, 0.f, 0.f};

    int k0 = kc * (H_DIM / 2), k1 = k0 + (H_DIM / 2);
    for (int kk = k0; kk < k1; kk += 32) {
        async_load16(gA0 + kk, lA0);
        async_load16(gA1 + kk, lA1);
        async_load16(gB0 + kk, lB0);
        async_load16(gB1 + kk, lB1);
        __syncthreads();
        short8 aF[4], bF[4];
#pragma unroll
        for (int t = 0; t < 4; ++t) {
            int ra = wm * 64 + t * 16 + l4;
            aF[t] = *(const short8*)(sAc + ra * 64 + ((q ^ ((ra >> 1) & 3)) << 4));
            int rb = wn * 64 + t * 16 + l4;
            bF[t] = *(const short8*)(sBc + rb * 64 + ((q ^ ((rb >> 1) & 3)) << 4));
        }
#pragma unroll
        for (int tm = 0; tm < 4; ++tm)
#pragma unroll
            for (int tn = 0; tn < 4; ++tn)
                acc[tm][tn] = __builtin_amdgcn_mfma_f32_16x16x32_bf16(aF[tm], bF[tn], acc[tm][tn], 0, 0, 0);
        __syncthreads();
    }

    size_t ybase = (size_t)kc * 2 * T;
    unsigned short* ys = (unsigned short*)ybuf;
#pragma unroll
    for (int tm = 0; tm < 4; ++tm) {
        int rbase = wm * 64 + tm * 16 + q * 4;
#pragma unroll
        for (int i = 0; i < 4; ++i) {
            int row = m0 + rbase + i;
            if (row < M) {
                size_t yrow = (ybase + sb + row) * D_DIM;
                ushort4v pk;
#pragma unroll
                for (int tn = 0; tn < 4; ++tn) pk[tn] = f2b(acc[tm][tn][i]);
                *(ushort4v*)(ys + yrow + n0 + wn * 64 + l4 * 4) = pk;
            }
        }
    }
}

// ---------------- combine: out[t, pi(c)] = sum_j w_j * (y_j(p0)+y_j(p1) + b2[e_j]) ----------------
__global__ __launch_bounds__(256) void combine_kernel(
    const __hip_bfloat16* __restrict__ yb, const float* __restrict__ b2,
    const int* __restrict__ base, const int* __restrict__ eidx,
    const float* __restrict__ ewgt, float* __restrict__ out, int T) {
    int t = blockIdx.x, tid = threadIdx.x;
    int v0 = eidx[2 * t], v1 = eidx[2 * t + 1];
    float w0 = ewgt[2 * t], w1 = ewgt[2 * t + 1];
    int e0 = v0 >> 16, e1 = v1 >> 16;
    size_t g0 = (size_t)base[e0] + (v0 & 0xffff);
    size_t g1 = (size_t)base[e1] + (v1 & 0xffff);
    int c = tid * 4;               // stored (permuted) col
    int blk = c >> 6;
    int tt = (c >> 2) & 15;
    size_t off2 = (size_t)2 * T * D_DIM;
    const short* ys = (const short*)yb;
    short4v a0 = *(const short4v*)(ys + g0 * D_DIM + c);
    short4v a1 = *(const short4v*)(ys + off2 + g0 * D_DIM + c);
    short4v c0 = *(const short4v*)(ys + g1 * D_DIM + c);
    short4v c1 = *(const short4v*)(ys + off2 + g1 * D_DIM + c);
    float s0[4] = { b2f(a0.x) + b2f(a1.x), b2f(a0.y) + b2f(a1.y),
                    b2f(a0.z) + b2f(a1.z), b2f(a0.w) + b2f(a1.w) };
    float s1[4] = { b2f(c0.x) + b2f(c1.x), b2f(c0.y) + b2f(c1.y),
                    b2f(c0.z) + b2f(c1.z), b2f(c0.w) + b2f(c1.w) };
    float* orow = out + (size_t)t * D_DIM;
#pragma unroll
    for (int s = 0; s < 4; ++s) {
        int oc = blk * 64 + s * 16 + tt;   // original col
        float o = w0 * (s0[s] + b2[(size_t)e0 * D_DIM + oc]) +
                  w1 * (s1[s] + b2[(size_t)e1 * D_DIM + oc]);
        orow[oc] = o;
    }
}

extern "C" void kernel_launch(void* const* d_in, const int* in_sizes, int n_in,
                              void* d_out, int out_size, void* d_ws, size_t ws_size,
                              hipStream_t stream) {
    const float* x  = (const float*)d_in[0];
    const float* Wg = (const float*)d_in[1];
    const float* W1 = (const float*)d_in[2];
    const float* b1 = (const float*)d_in[3];
    const float* W2 = (const float*)d_in[4];
    const float* b2 = (const float*)d_in[5];
    int T = in_sizes[0] / D_DIM;  // 8192

    char* p = (char*)d_ws;
    int* cnt   = (int*)p;
    int* base  = (int*)(p + 256);
    int* tok   = (int*)(p + 512);
    int* eidx  = (int*)(p + 512 + 4ll * E_NUM * T);
    float* ewgt = (float*)(p + 512 + 4ll * E_NUM * T + 8ll * T);
    int* epick = (int*)(p + 512 + 4ll * E_NUM * T + 16ll * T);
    char* pb = p + 512 + 4ll * E_NUM * T + 20ll * T;
    __hip_bfloat16* xb  = (__hip_bfloat16*)pb;
    __hip_bfloat16* w1t = xb + (size_t)T * D_DIM;
    __hip_bfloat16* w2t = w1t + (size_t)E_NUM * H_DIM * D_DIM;
    __hip_bfloat16* hb  = w2t + (size_t)E_NUM * H_DIM * D_DIM;
    // ybuf [2][2T][D] bf16 (67 MB) aliases xb+w1t (dead by gemm2 time).
    __hip_bfloat16* yb  = xb;

    hipMemsetAsync(cnt, 0, 256, stream);

    router_kernel<<<dim3((T + 3) / 4), 256, 0, stream>>>(x, Wg, xb, epick, ewgt, T);
    bucket_kernel<<<dim3(T / 128), 256, 0, stream>>>(epick, cnt, tok, eidx, T);
    prefix_kernel<<<1, 64, 0, stream>>>(cnt, base);
    transpose_both_kernel<<<dim3(2048, 1, E_NUM), dim3(32, 8), 0, stream>>>(W1, W2, w1t, w2t);
    gemm1_kernel<<<dim3(H_DIM / 128, T / 128, E_NUM), 256, 0, stream>>>(xb, w1t, b1, cnt, base, tok, hb, T);
    gemm2_kernel<<<dim3(D_DIM / 128, T / 128, E_NUM * 2), 256, 0, stream>>>(hb, w2t, cnt, base, yb, T);
    combine_kernel<<<T, 256, 0, stream>>>(yb, b2, base, eidx, ewgt, (float*)d_out, T);
}